// Round 1
// baseline (980.081 us; speedup 1.0000x reference)
//
#include <hip/hip_runtime.h>

#define N_NODES 100000
#define N_EDGES 600000
#define K_DIM   128
#define NPART   ((N_NODES + 255) / 256)   // 391 scan blocks

// ---------------------------------------------------------------- CSR build

__global__ void deg_kernel(const int* __restrict__ dst, int* __restrict__ deg) {
  int e = blockIdx.x * blockDim.x + threadIdx.x;
  if (e < N_EDGES) atomicAdd(&deg[dst[e]], 1);
}

__global__ void scan1_kernel(const int* __restrict__ deg, int* __restrict__ excl,
                             int* __restrict__ partials) {
  __shared__ int s[256];
  int t = threadIdx.x, i = blockIdx.x * 256 + t;
  int v = (i < N_NODES) ? deg[i] : 0;
  s[t] = v;
  __syncthreads();
  for (int off = 1; off < 256; off <<= 1) {
    int x = (t >= off) ? s[t - off] : 0;
    __syncthreads();
    s[t] += x;
    __syncthreads();
  }
  if (i < N_NODES) excl[i] = s[t] - v;
  if (t == 255) partials[blockIdx.x] = s[t];
}

__global__ void scan2_kernel(int* __restrict__ partials) {
  __shared__ int s[512];
  int t = threadIdx.x;
  int v = (t < NPART) ? partials[t] : 0;
  s[t] = v;
  __syncthreads();
  for (int off = 1; off < 512; off <<= 1) {
    int x = (t >= off) ? s[t - off] : 0;
    __syncthreads();
    s[t] += x;
    __syncthreads();
  }
  if (t < NPART) partials[t] = s[t] - v;   // exclusive block offsets
}

__global__ void scan3_kernel(const int* __restrict__ excl, const int* __restrict__ partials,
                             const int* __restrict__ deg, int* __restrict__ row_ptr,
                             int* __restrict__ cursor, float* __restrict__ inv_deg) {
  int i = blockIdx.x * blockDim.x + threadIdx.x;
  if (i < N_NODES) {
    int rp = excl[i] + partials[i >> 8];
    row_ptr[i] = rp;
    cursor[i] = rp;
    inv_deg[i] = 1.0f / (float)(deg[i] > 1 ? deg[i] : 1);
  } else if (i == N_NODES) {
    row_ptr[N_NODES] = N_EDGES;
  }
}

__global__ void fill_kernel(const int* __restrict__ src, const int* __restrict__ dst,
                            int* __restrict__ cursor, int* __restrict__ ssrc) {
  int e = blockIdx.x * blockDim.x + threadIdx.x;
  if (e < N_EDGES) {
    int p = atomicAdd(&cursor[dst[e]], 1);
    ssrc[p] = src[e];
  }
}

// ---------------------------------------------------------------- fused SAGE layer
// out[v] = act( H[v] @ Ws + (inv_deg[v] * sum_{u->v} H[u]) @ Wn + b )
// Block: 128 rows x DOUT cols, 256 threads, thread = 4 rows x (DOUT/8) cols.
// Gather phase fills sAgg (scaled agg rows) in LDS; two k-passes share one sW buffer.

template <int DOUT, bool RELU>
__global__ __launch_bounds__(256, 1) void sage_kernel(
    const float* __restrict__ H, const float* __restrict__ Ws,
    const float* __restrict__ Wn, const float* __restrict__ bias,
    const int* __restrict__ row_ptr, const int* __restrict__ ssrc,
    const float* __restrict__ inv_deg, float* __restrict__ out) {
  constexpr int CPT = DOUT / 8;   // cols per thread (16 or 8)
  constexpr int NI  = CPT / 4;    // float4 groups (4 or 2)
  __shared__ float sW[K_DIM * DOUT];
  __shared__ float sAgg[128 * 132];   // +4 pad: breaks pow-2 bank stride

  const int tid  = threadIdx.x;
  const int cg   = tid & 7;    // 8 col groups
  const int rg   = tid >> 3;   // 32 row groups
  const int row0 = blockIdx.x * 128;

  // stage Ws (in flight alongside gather loads)
  #pragma unroll
  for (int i = tid * 4; i < K_DIM * DOUT; i += 1024)
    *(float4*)&sW[i] = *(const float4*)&Ws[i];

  // ---- gather: 8 lanes per row read contiguous 512B src rows; 4 row passes
  for (int rbase = 0; rbase < 128; rbase += 32) {
    const int rl = rbase + rg;
    const int v  = row0 + rl;
    float a[16];
    #pragma unroll
    for (int i = 0; i < 16; ++i) a[i] = 0.f;
    if (v < N_NODES) {
      const int beg = row_ptr[v], end = row_ptr[v + 1];
      for (int e = beg; e < end; ++e) {
        const float* __restrict__ hp = H + (size_t)ssrc[e] * K_DIM;
        #pragma unroll
        for (int i = 0; i < 4; ++i) {
          const float4 t = *(const float4*)(hp + cg * 4 + i * 32);
          a[4 * i + 0] += t.x; a[4 * i + 1] += t.y;
          a[4 * i + 2] += t.z; a[4 * i + 3] += t.w;
        }
      }
      const float sc = inv_deg[v];
      #pragma unroll
      for (int i = 0; i < 16; ++i) a[i] *= sc;
    }
    #pragma unroll
    for (int i = 0; i < 4; ++i)
      *(float4*)&sAgg[rl * 132 + cg * 4 + i * 32] =
          make_float4(a[4 * i], a[4 * i + 1], a[4 * i + 2], a[4 * i + 3]);
  }
  __syncthreads();

  const int r0 = rg * 4;
  float acc[4][CPT];
  #pragma unroll
  for (int r = 0; r < 4; ++r)
    #pragma unroll
    for (int c = 0; c < CPT; ++c) acc[r][c] = 0.f;

  const float* __restrict__ hbase[4];
  #pragma unroll
  for (int r = 0; r < 4; ++r) {
    int v = row0 + r0 + r;
    v = v < N_NODES ? v : N_NODES - 1;   // clamp loads; stores guarded
    hbase[r] = H + (size_t)v * K_DIM;
  }

  // ---- pass 1: self path (H from global, Ws from LDS)
  for (int kk = 0; kk < K_DIM; kk += 4) {
    float4 h4[4];
    #pragma unroll
    for (int r = 0; r < 4; ++r) h4[r] = *(const float4*)(hbase[r] + kk);
    #pragma unroll
    for (int kq = 0; kq < 4; ++kq) {
      float4 w4[NI];
      #pragma unroll
      for (int i = 0; i < NI; ++i)
        w4[i] = *(const float4*)&sW[(kk + kq) * DOUT + cg * 4 + i * 32];
      #pragma unroll
      for (int r = 0; r < 4; ++r) {
        const float h = ((const float*)&h4[r])[kq];
        #pragma unroll
        for (int i = 0; i < NI; ++i) {
          acc[r][4 * i + 0] = fmaf(h, w4[i].x, acc[r][4 * i + 0]);
          acc[r][4 * i + 1] = fmaf(h, w4[i].y, acc[r][4 * i + 1]);
          acc[r][4 * i + 2] = fmaf(h, w4[i].z, acc[r][4 * i + 2]);
          acc[r][4 * i + 3] = fmaf(h, w4[i].w, acc[r][4 * i + 3]);
        }
      }
    }
  }

  // ---- swap weights: Wn into the same LDS buffer
  __syncthreads();
  #pragma unroll
  for (int i = tid * 4; i < K_DIM * DOUT; i += 1024)
    *(float4*)&sW[i] = *(const float4*)&Wn[i];
  __syncthreads();

  // ---- pass 2: neighbor path (agg rows from LDS, Wn from LDS)
  for (int kk = 0; kk < K_DIM; kk += 4) {
    float4 h4[4];
    #pragma unroll
    for (int r = 0; r < 4; ++r)
      h4[r] = *(const float4*)&sAgg[(r0 + r) * 132 + kk];
    #pragma unroll
    for (int kq = 0; kq < 4; ++kq) {
      float4 w4[NI];
      #pragma unroll
      for (int i = 0; i < NI; ++i)
        w4[i] = *(const float4*)&sW[(kk + kq) * DOUT + cg * 4 + i * 32];
      #pragma unroll
      for (int r = 0; r < 4; ++r) {
        const float h = ((const float*)&h4[r])[kq];
        #pragma unroll
        for (int i = 0; i < NI; ++i) {
          acc[r][4 * i + 0] = fmaf(h, w4[i].x, acc[r][4 * i + 0]);
          acc[r][4 * i + 1] = fmaf(h, w4[i].y, acc[r][4 * i + 1]);
          acc[r][4 * i + 2] = fmaf(h, w4[i].z, acc[r][4 * i + 2]);
          acc[r][4 * i + 3] = fmaf(h, w4[i].w, acc[r][4 * i + 3]);
        }
      }
    }
  }

  // ---- epilogue: bias (+ReLU), coalesced float4 stores
  #pragma unroll
  for (int i = 0; i < NI; ++i) {
    const float4 b4 = *(const float4*)&bias[cg * 4 + i * 32];
    #pragma unroll
    for (int r = 0; r < 4; ++r) {
      const int v = row0 + r0 + r;
      if (v < N_NODES) {
        float4 o;
        o.x = acc[r][4 * i + 0] + b4.x;
        o.y = acc[r][4 * i + 1] + b4.y;
        o.z = acc[r][4 * i + 2] + b4.z;
        o.w = acc[r][4 * i + 3] + b4.w;
        if (RELU) {
          o.x = o.x > 0.f ? o.x : 0.f;
          o.y = o.y > 0.f ? o.y : 0.f;
          o.z = o.z > 0.f ? o.z : 0.f;
          o.w = o.w > 0.f ? o.w : 0.f;
        }
        *(float4*)&out[(size_t)v * DOUT + cg * 4 + i * 32] = o;
      }
    }
  }
}

// ---------------------------------------------------------------- plain FC layer
// out = relu(H @ W + b), 128x128

template <bool RELU>
__global__ __launch_bounds__(256, 2) void fc_kernel(
    const float* __restrict__ H, const float* __restrict__ W,
    const float* __restrict__ bias, float* __restrict__ out) {
  constexpr int DOUT = 128, CPT = 16, NI = 4;
  __shared__ float sW[K_DIM * DOUT];

  const int tid  = threadIdx.x;
  const int cg   = tid & 7;
  const int rg   = tid >> 3;
  const int row0 = blockIdx.x * 128;

  #pragma unroll
  for (int i = tid * 4; i < K_DIM * DOUT; i += 1024)
    *(float4*)&sW[i] = *(const float4*)&W[i];
  __syncthreads();

  const int r0 = rg * 4;
  float acc[4][CPT];
  #pragma unroll
  for (int r = 0; r < 4; ++r)
    #pragma unroll
    for (int c = 0; c < CPT; ++c) acc[r][c] = 0.f;

  const float* __restrict__ hbase[4];
  #pragma unroll
  for (int r = 0; r < 4; ++r) {
    int v = row0 + r0 + r;
    v = v < N_NODES ? v : N_NODES - 1;
    hbase[r] = H + (size_t)v * K_DIM;
  }

  for (int kk = 0; kk < K_DIM; kk += 4) {
    float4 h4[4];
    #pragma unroll
    for (int r = 0; r < 4; ++r) h4[r] = *(const float4*)(hbase[r] + kk);
    #pragma unroll
    for (int kq = 0; kq < 4; ++kq) {
      float4 w4[NI];
      #pragma unroll
      for (int i = 0; i < NI; ++i)
        w4[i] = *(const float4*)&sW[(kk + kq) * DOUT + cg * 4 + i * 32];
      #pragma unroll
      for (int r = 0; r < 4; ++r) {
        const float h = ((const float*)&h4[r])[kq];
        #pragma unroll
        for (int i = 0; i < NI; ++i) {
          acc[r][4 * i + 0] = fmaf(h, w4[i].x, acc[r][4 * i + 0]);
          acc[r][4 * i + 1] = fmaf(h, w4[i].y, acc[r][4 * i + 1]);
          acc[r][4 * i + 2] = fmaf(h, w4[i].z, acc[r][4 * i + 2]);
          acc[r][4 * i + 3] = fmaf(h, w4[i].w, acc[r][4 * i + 3]);
        }
      }
    }
  }

  #pragma unroll
  for (int i = 0; i < NI; ++i) {
    const float4 b4 = *(const float4*)&bias[cg * 4 + i * 32];
    #pragma unroll
    for (int r = 0; r < 4; ++r) {
      const int v = row0 + r0 + r;
      if (v < N_NODES) {
        float4 o;
        o.x = acc[r][4 * i + 0] + b4.x;
        o.y = acc[r][4 * i + 1] + b4.y;
        o.z = acc[r][4 * i + 2] + b4.z;
        o.w = acc[r][4 * i + 3] + b4.w;
        if (RELU) {
          o.x = o.x > 0.f ? o.x : 0.f;
          o.y = o.y > 0.f ? o.y : 0.f;
          o.z = o.z > 0.f ? o.z : 0.f;
          o.w = o.w > 0.f ? o.w : 0.f;
        }
        *(float4*)&out[(size_t)v * DOUT + cg * 4 + i * 32] = o;
      }
    }
  }
}

// ---------------------------------------------------------------- launcher

extern "C" void kernel_launch(void* const* d_in, const int* in_sizes, int n_in,
                              void* d_out, int out_size, void* d_ws, size_t ws_size,
                              hipStream_t stream) {
  const float* x        = (const float*)d_in[0];
  const int*   src      = (const int*)d_in[1];
  const int*   dst      = (const int*)d_in[2];
  const float* w_self0  = (const float*)d_in[3];
  const float* b_self0  = (const float*)d_in[4];
  const float* w_neigh0 = (const float*)d_in[5];
  const float* fc_w     = (const float*)d_in[6];
  const float* fc_b     = (const float*)d_in[7];
  const float* fc2_w    = (const float*)d_in[8];
  const float* fc2_b    = (const float*)d_in[9];
  const float* w_self1  = (const float*)d_in[10];
  const float* b_self1  = (const float*)d_in[11];
  const float* w_neigh1 = (const float*)d_in[12];
  const float* w_self2  = (const float*)d_in[13];
  const float* b_self2  = (const float*)d_in[14];
  const float* w_neigh2 = (const float*)d_in[15];

  char* p = (char*)d_ws;
  auto carve = [&](size_t bytes) {
    void* q = (void*)p;
    p += (bytes + 511) & ~(size_t)511;
    return q;
  };
  float* F0      = (float*)carve((size_t)N_NODES * 128 * 4);
  float* F1      = (float*)carve((size_t)N_NODES * 128 * 4);
  int*   ssrc    = (int*)carve((size_t)N_EDGES * 4);
  int*   row_ptr = (int*)carve((size_t)(N_NODES + 1) * 4);
  int*   cursor  = (int*)carve((size_t)N_NODES * 4);
  int*   deg     = (int*)carve((size_t)N_NODES * 4);
  int*   excl    = (int*)carve((size_t)N_NODES * 4);
  int*   parts   = (int*)carve(512 * 4);
  float* inv_deg = (float*)carve((size_t)N_NODES * 4);

  // ---- CSR build (by dst)
  hipMemsetAsync(deg, 0, (size_t)N_NODES * 4, stream);
  const int EB = (N_EDGES + 255) / 256;
  deg_kernel<<<EB, 256, 0, stream>>>(dst, deg);
  scan1_kernel<<<NPART, 256, 0, stream>>>(deg, excl, parts);
  scan2_kernel<<<1, 512, 0, stream>>>(parts);
  scan3_kernel<<<((N_NODES + 1) + 255) / 256, 256, 0, stream>>>(excl, parts, deg,
                                                                row_ptr, cursor, inv_deg);
  fill_kernel<<<EB, 256, 0, stream>>>(src, dst, cursor, ssrc);

  // ---- network
  const int GB = (N_NODES + 127) / 128;
  // layer 0: SAGE + ReLU -> F0
  sage_kernel<128, true><<<GB, 256, 0, stream>>>(x, w_self0, w_neigh0, b_self0,
                                                 row_ptr, ssrc, inv_deg, F0);
  // NGNN inner fc layers
  fc_kernel<true><<<GB, 256, 0, stream>>>(F0, fc_w, fc_b, F1);
  fc_kernel<true><<<GB, 256, 0, stream>>>(F1, fc2_w, fc2_b, F0);
  // layer 1: SAGE + ReLU -> F1
  sage_kernel<128, true><<<GB, 256, 0, stream>>>(F0, w_self1, w_neigh1, b_self1,
                                                 row_ptr, ssrc, inv_deg, F1);
  // layer 2: SAGE (no act) -> d_out
  sage_kernel<64, false><<<GB, 256, 0, stream>>>(F1, w_self2, w_neigh2, b_self2,
                                                 row_ptr, ssrc, inv_deg, (float*)d_out);
}